// Round 7
// baseline (192.739 us; speedup 1.0000x reference)
//
#include <hip/hip_runtime.h>
#include <stdint.h>

typedef __bf16 bf16;
typedef __attribute__((ext_vector_type(8))) __bf16 bf16x8;
typedef __attribute__((ext_vector_type(4))) __bf16 bf16x4;
typedef __attribute__((ext_vector_type(4))) float  f32x4;

#define ATT_SCALE 0.125f   // 1/sqrt(64), folded into Q at GEMM epilogue

// ---------------------------------------------------------------------------
// async 16B global -> LDS (wave-uniform LDS base + lane*16, per-lane gaddr)
// ---------------------------------------------------------------------------
__device__ __forceinline__ void async16(void* lds, const void* g) {
  __builtin_amdgcn_global_load_lds(
      (__attribute__((address_space(1))) void*)(void*)g,
      (__attribute__((address_space(3))) void*)lds,
      16, 0, 0);
}

// ---------------------------------------------------------------------------
// Fused prep: blocks [0,3072) convert x fp32->bf16 (8 elems/thread);
//             blocks [3072,4800) transpose W [768x2304] fp32 -> Wt bf16.
// ---------------------------------------------------------------------------
__global__ void prep_kernel(const float* __restrict__ x, bf16* __restrict__ y,
                            const float* __restrict__ W, bf16* __restrict__ Wt) {
  __shared__ float tile[32][33];
  const int tid = threadIdx.x;
  if (blockIdx.x < 3072) {
    size_t i = ((size_t)blockIdx.x * 256 + tid) * 8;
    float4 a = *(const float4*)(x + i);
    float4 b = *(const float4*)(x + i + 4);
    bf16x8 o;
    o[0] = (bf16)a.x; o[1] = (bf16)a.y; o[2] = (bf16)a.z; o[3] = (bf16)a.w;
    o[4] = (bf16)b.x; o[5] = (bf16)b.y; o[6] = (bf16)b.z; o[7] = (bf16)b.w;
    *(bf16x8*)(y + i) = o;
  } else {
    const int bid = blockIdx.x - 3072;        // 0..1727
    const int tx = tid & 31, ty = tid >> 5;   // 32 x 8
    const int n0 = (bid % 72) * 32, k0 = (bid / 72) * 32;
#pragma unroll
    for (int r = 0; r < 4; ++r)
      tile[ty + r * 8][tx] = W[(size_t)(k0 + ty + r * 8) * 2304 + n0 + tx];
    __syncthreads();
#pragma unroll
    for (int r = 0; r < 4; ++r)
      Wt[(size_t)(n0 + ty + r * 8) * 768 + k0 + tx] = (bf16)tile[tx][ty + r * 8];
  }
}

// ---------------------------------------------------------------------------
// QKV GEMM v3 (unchanged from R6, 42.3 us steady): 128x128 tile, BK=64,
//   XCD swizzle (FETCH 70->48 MB), counted-vmcnt two-barrier K-loop.
// ---------------------------------------------------------------------------
__global__ void qkv_gemm_kernel(const bf16* __restrict__ A, const bf16* __restrict__ Bw,
                                const float* __restrict__ bias,
                                bf16* __restrict__ Qo, bf16* __restrict__ Ko,
                                bf16* __restrict__ Vo) {
  __shared__ __align__(16) char lds[65536];   // 2 x (A 16KB + B 16KB)

  const int tid  = threadIdx.x;
  const int wave = tid >> 6, lane = tid & 63;
  const int quad = lane >> 4, mn = lane & 15;
  const int wr = wave >> 1, wc = wave & 1;

  // XCD swizzle: orig dispatch id -> contiguous per-XCD chunk (144 blocks)
  const int orig = blockIdx.y * 18 + blockIdx.x;   // hw flat id (x fastest)
  const int swz  = (orig & 7) * 144 + (orig >> 3); // 1152 = 8 * 144, bijective
  const int m0 = (swz / 18) * 128;
  const int n0 = (swz % 18) * 128;

  f32x4 acc[4][4] = {};

  const int lrow = lane >> 3;           // 0..7  (row within 8-row group)
  const int cg   = (lane & 7) ^ lrow;   // global 16B-chunk index (swizzled)

  auto stage = [&](int kt, char* buf) {
    char* Al = buf;
    char* Bl = buf + 16384;
#pragma unroll
    for (int u = 0; u < 4; ++u) {
      const int t   = wave * 4 + u;      // 8-row group 0..15
      const int row = t * 8 + lrow;      // tile row 0..127
      async16(Al + t * 1024 + lane * 16,
              A  + (size_t)(m0 + row) * 768 + kt + cg * 8);
      async16(Bl + t * 1024 + lane * 16,
              Bw + (size_t)(n0 + row) * 768 + kt + cg * 8);
    }
  };

#define SCHED0() __builtin_amdgcn_sched_barrier(0)

  stage(0, lds); SCHED0();

  for (int j = 0; j < 12; ++j) {
    // BAR-A: all waves finished iter j-1 LDS reads (WAR gate for buf (j+1)&1)
    asm volatile("s_waitcnt lgkmcnt(0)" ::: "memory"); SCHED0();
    __builtin_amdgcn_s_barrier(); SCHED0();
    if (j < 11) { stage((j + 1) * 64, lds + ((j + 1) & 1) * 32768); SCHED0(); }
    // complete own stage j (8 loads); leave stage j+1 in flight
    if (j < 11) { asm volatile("s_waitcnt vmcnt(8)" ::: "memory"); }
    else        { asm volatile("s_waitcnt vmcnt(0)" ::: "memory"); }
    SCHED0();
    __builtin_amdgcn_s_barrier(); SCHED0();   // BAR-B: publish stage j

    char* Al = lds + (j & 1) * 32768;
    char* Bl = Al + 16384;

#pragma unroll
    for (int s = 0; s < 2; ++s) {        // two K=32 steps within BK=64
      bf16x8 af[4], bfr[4];
      const int csw = ((s * 4 + quad) ^ (mn & 7)) * 16;  // swizzled chunk offset
#pragma unroll
      for (int i = 0; i < 4; ++i) {
        af[i]  = *(const bf16x8*)(Al + (wr * 64 + i * 16 + mn) * 128 + csw);
        bfr[i] = *(const bf16x8*)(Bl + (wc * 64 + i * 16 + mn) * 128 + csw);
      }
#pragma unroll
      for (int i = 0; i < 4; ++i)
#pragma unroll
        for (int jj = 0; jj < 4; ++jj)
          acc[i][jj] = __builtin_amdgcn_mfma_f32_16x16x32_bf16(af[i], bfr[jj], acc[i][jj], 0, 0, 0);
    }
  }

#undef SCHED0

  // epilogue
  const int ng    = n0 + wc * 64;
  const int third = ng / 768;           // 0=Q 1=K 2=V
  const int nmod  = ng % 768;
  const float sc  = (third == 0) ? ATT_SCALE : 1.0f;
#pragma unroll
  for (int ct = 0; ct < 4; ++ct) {
    int n = nmod + ct * 16 + mn;
    int h = n >> 6, d = n & 63;
    float bv = bias[third * 768 + n];
#pragma unroll
    for (int rt = 0; rt < 4; ++rt) {
      int m  = m0 + wr * 64 + rt * 16 + quad * 4;
      int b  = m >> 10, t0 = m & 1023;
      size_t bh = (size_t)b * 12 + h;
      if (third == 2) {
        bf16x4 pk;
#pragma unroll
        for (int r = 0; r < 4; ++r) pk[r] = (bf16)(acc[rt][ct][r] + bv);
        *(bf16x4*)(Vo + (bh * 64 + d) * 1024 + t0) = pk;   // V^T
      } else {
        bf16* dst = (third == 0 ? Qo : Ko) + (bh * 1024 + t0) * 64 + d;
#pragma unroll
        for (int r = 0; r < 4; ++r) dst[(size_t)r * 64] = (bf16)((acc[rt][ct][r] + bv) * sc);
      }
    }
  }
}

// ---------------------------------------------------------------------------
// Attention v8: NO KV LDS staging. Cross-round accounting showed v5/v6/v7
//   (all staging-pipeline variants) identical within noise -> staging was
//   never the lever. K/V total = 24 MB, fully L2-resident (32 MB aggregate);
//   per guide m169 (same S=1024 shape) LDS-staging L2-fit data is pure
//   overhead. v8 loads K/V fragments DIRECTLY global->VGPR (addresses =
//   the staged path's swizzle inverted, so fragment contents are identical):
//     kf[ct][h] = K[j*64+ct*16+mn][h*32+quad*8 ..+8]
//     vf[ct][h] = V^T[ct*16+mn][j*64+h*32+quad*8 ..+8]
//   This deletes all staging DMA, ALL barriers (S buffer is wave-private),
//   and the vmcnt machinery: waves progress independently, causal imbalance
//   self-levels, and the CU's 12 waves share tiles via L1/L2. LDS = 16 KB
//   S buffer only (8B-chunk XOR swizzle, <=2-way, as before). Phase split
//   QK(A),QK(B),SV(A),SV(B) retained: B's QK covers A's S round-trip.
// ---------------------------------------------------------------------------
__global__ __launch_bounds__(256, 3)
void attn_kernel(const bf16* __restrict__ Q, const bf16* __restrict__ K,
                 const bf16* __restrict__ Vt, float* __restrict__ out) {
  __shared__ __align__(16) char ldsS[16384];   // 128 rows x 128B (A-half, B-half)

  const int tid  = threadIdx.x;
  const int wave = tid >> 6, lane = tid & 63;
  const int quad = lane >> 4, mn = lane & 15;
  const int bh  = blockIdx.x;
  const int qta = blockIdx.y;            // 0..7
  const int qtb = 15 - qta;              // 8..15
  const int qa0 = qta * 64, qb0 = qtb * 64;

  const bf16* Qg  = Q  + (size_t)bh * 65536;
  const bf16* Kg0 = K  + (size_t)bh * 65536;
  const bf16* Vg0 = Vt + (size_t)bh * 65536;

  // Q fragments: lane mn -> row base+mn, d = quad*8.. / 32+quad*8..
  bf16x8 qfA[2], qfB[2];
  {
    const bf16* ra = Qg + (size_t)(qa0 + wave * 16 + mn) * 64;
    qfA[0] = *(const bf16x8*)(ra + quad * 8);
    qfA[1] = *(const bf16x8*)(ra + 32 + quad * 8);
    const bf16* rb = Qg + (size_t)(qb0 + wave * 16 + mn) * 64;
    qfB[0] = *(const bf16x8*)(rb + quad * 8);
    qfB[1] = *(const bf16x8*)(rb + 32 + quad * 8);
  }

  f32x4 yA[4] = {}, yB[4] = {};

  const int srow = (wave * 16 + mn) * 128;   // within a half (half adds 8192)
  const int sw = mn & 7;

  for (int j = 0; j <= qtb; ++j) {
    // K/V fragments straight from global (L2-resident; contents identical
    // to the old staged+swizzled LDS reads)
    bf16x8 kf[4][2], vf[4][2];
#pragma unroll
    for (int ct = 0; ct < 4; ++ct) {
      const bf16* kr = Kg0 + (size_t)(j * 64 + ct * 16 + mn) * 64 + quad * 8;
      kf[ct][0] = *(const bf16x8*)(kr);
      kf[ct][1] = *(const bf16x8*)(kr + 32);
      const bf16* vr = Vg0 + (size_t)(ct * 16 + mn) * 1024 + j * 64 + quad * 8;
      vf[ct][0] = *(const bf16x8*)(vr);
      vf[ct][1] = *(const bf16x8*)(vr + 32);
    }

    auto qk_half = [&](const bf16x8* qf, int half, int qrow, bool diag) {
      // S^T = K Q^T: lane holds (kk = j*64+ct*16+quad*4+r, q = qrow=base+mn)
#pragma unroll
      for (int ct = 0; ct < 4; ++ct) {
        f32x4 a = {};
        a = __builtin_amdgcn_mfma_f32_16x16x32_bf16(kf[ct][0], qf[0], a, 0, 0, 0);
        a = __builtin_amdgcn_mfma_f32_16x16x32_bf16(kf[ct][1], qf[1], a, 0, 0, 0);
        const int kkg = j * 64 + ct * 16 + quad * 4;
        bf16x4 pk;
#pragma unroll
        for (int r = 0; r < 4; ++r) {
          float v = a[r];
          v = v > 0.f ? v : 0.f;
          if (diag && kkg + r > qrow) v = 0.f;
          pk[r] = (bf16)v;
        }
        *(bf16x4*)(ldsS + half * 8192 + srow +
                   (((ct * 4 + quad) ^ (sw << 1)) & 15) * 8) = pk;
      }
    };
    auto sv_half = [&](f32x4* y, int half) {
#pragma unroll
      for (int kb = 0; kb < 2; ++kb) {
        bf16x8 sf = *(const bf16x8*)(ldsS + half * 8192 + srow +
                                     ((kb * 4 + quad) ^ sw) * 16);
#pragma unroll
        for (int ct = 0; ct < 4; ++ct)
          y[ct] = __builtin_amdgcn_mfma_f32_16x16x32_bf16(sf, vf[ct][kb], y[ct], 0, 0, 0);
      }
    };

    if (j <= qta) qk_half(qfA, 0, qa0 + wave * 16 + mn, j == qta);
    qk_half(qfB, 1, qb0 + wave * 16 + mn, j == qtb);
    if (j <= qta) sv_half(yA, 0);
    sv_half(yB, 1);
  }

  // write out: out[b][t][h*64+d]; yacc: q = wave*16+quad*4+r, d = ct*16+mn
  const int b = bh / 12, h = bh % 12;
  {
    float* ob = out + ((size_t)b * 1024 + qa0 + wave * 16 + quad * 4) * 768 + h * 64;
#pragma unroll
    for (int ct = 0; ct < 4; ++ct)
#pragma unroll
      for (int r = 0; r < 4; ++r)
        ob[(size_t)r * 768 + ct * 16 + mn] = yA[ct][r];
  }
  {
    float* ob = out + ((size_t)b * 1024 + qb0 + wave * 16 + quad * 4) * 768 + h * 64;
#pragma unroll
    for (int ct = 0; ct < 4; ++ct)
#pragma unroll
      for (int r = 0; r < 4; ++r)
        ob[(size_t)r * 768 + ct * 16 + mn] = yB[ct][r];
  }
}

// ---------------------------------------------------------------------------
extern "C" void kernel_launch(void* const* d_in, const int* in_sizes, int n_in,
                              void* d_out, int out_size, void* d_ws, size_t ws_size,
                              hipStream_t stream) {
  const float* x    = (const float*)d_in[0];   // [8,1024,768]
  const float* W    = (const float*)d_in[1];   // [768,2304]
  const float* bias = (const float*)d_in[2];   // [2304]
  float* out = (float*)d_out;                  // [8,1024,768]

  char* ws = (char*)d_ws;
  bf16* xb = (bf16*)(ws);                      // 8192*768
  bf16* Wt = (bf16*)(ws + 12582912);           // 2304*768
  bf16* Qb = (bf16*)(ws + 16121856);           // 96*1024*64
  bf16* Kb = (bf16*)(ws + 28704768);           // 96*1024*64
  bf16* Vb = (bf16*)(ws + 41287680);           // 96*64*1024 (V^T)

  prep_kernel<<<4800, 256, 0, stream>>>(x, xb, W, Wt);
  qkv_gemm_kernel<<<dim3(18, 64), 256, 0, stream>>>(xb, Wt, bias, Qb, Kb, Vb);
  attn_kernel<<<dim3(96, 8), 256, 0, stream>>>(Qb, Kb, Vb, out);
}